// Round 1
// baseline (1478.752 us; speedup 1.0000x reference)
//
#include <hip/hip_runtime.h>
#include <cstdint>
#include <cstddef>

// Problem constants
#define B_ 4
#define L_ 4096
#define D_ 1024
#define M_ (B_ * L_)          // 16384 rows
#define LN_EPS 1e-5f
#define SCAN_EPS 1e-8f
#define CT 64                 // scan chunk length
#define NC (L_ / CT)          // 64 chunks per sequence

// ---------------------------------------------------------------------------
// LayerNorm over last dim: one block (256 threads) per row of 1024 floats.
// ---------------------------------------------------------------------------
__global__ __launch_bounds__(256) void ln_kernel(
    const float* __restrict__ X, const float* __restrict__ gamma,
    const float* __restrict__ beta, float* __restrict__ Z)
{
    const int row = blockIdx.x;
    const int tid = threadIdx.x;
    const float* x = X + (size_t)row * D_;

    float4 v = *reinterpret_cast<const float4*>(x + tid * 4);
    float s = v.x + v.y + v.z + v.w;
    #pragma unroll
    for (int off = 32; off > 0; off >>= 1) s += __shfl_down(s, off);

    __shared__ float red[4];
    __shared__ float red2[4];
    const int wid = tid >> 6, lane = tid & 63;
    if (lane == 0) red[wid] = s;
    __syncthreads();
    const float mean = (red[0] + red[1] + red[2] + red[3]) * (1.0f / D_);

    const float dx = v.x - mean, dy = v.y - mean, dz = v.z - mean, dw = v.w - mean;
    float s2 = dx * dx + dy * dy + dz * dz + dw * dw;
    #pragma unroll
    for (int off = 32; off > 0; off >>= 1) s2 += __shfl_down(s2, off);
    if (lane == 0) red2[wid] = s2;
    __syncthreads();
    const float var = (red2[0] + red2[1] + red2[2] + red2[3]) * (1.0f / D_);
    const float rs = rsqrtf(var + LN_EPS);

    float4 g  = *reinterpret_cast<const float4*>(gamma + tid * 4);
    float4 be = *reinterpret_cast<const float4*>(beta + tid * 4);
    float4 z;
    z.x = dx * rs * g.x + be.x;
    z.y = dy * rs * g.y + be.y;
    z.z = dz * rs * g.z + be.z;
    z.w = dw * rs * g.w + be.w;
    *reinterpret_cast<float4*>(Z + (size_t)row * D_ + tid * 4) = z;
}

// ---------------------------------------------------------------------------
// Fused triple GEMM: G[m, e'] = dot(Z[m,:], W[e,:]) + bias, e' in [0,3072).
// which = e'/1024 selects {Wa->sigmoid->A, Wb->Bx, Wc->C}.
// 128x128 output tile, BK=16, 256 threads, 8x8 accum per thread. fp32 FMA.
// ---------------------------------------------------------------------------
#define GBM 128
#define GBN 128
#define GBK 16
#define LDSP (GBM + 4)   // 132 floats row stride: keeps float4 alignment, breaks pow2 banks

__global__ __launch_bounds__(256) void gemm3_kernel(
    const float* __restrict__ Z,
    const float* __restrict__ Wa, const float* __restrict__ ba,
    const float* __restrict__ Wb, const float* __restrict__ bb,
    const float* __restrict__ Wc, const float* __restrict__ bc,
    float* __restrict__ Aout, float* __restrict__ Bxout, float* __restrict__ Cout)
{
    __shared__ float Zs[GBK][LDSP];
    __shared__ float Ws[GBK][LDSP];

    const int tid = threadIdx.x;
    const int m0 = blockIdx.y * GBM;
    const int n0 = blockIdx.x * GBN;        // global col in [0,3072)
    const int which = n0 >> 10;             // 0,1,2  (1024 % 128 == 0 so uniform per block)
    const int ncol0 = n0 & 1023;

    const float* __restrict__ W    = (which == 0) ? Wa : (which == 1) ? Wb : Wc;
    const float* __restrict__ bias = (which == 0) ? ba : (which == 1) ? bb : bc;

    const int tr = tid >> 4;    // 0..15 -> rows tr*8..tr*8+7
    const int tc = tid & 15;    // 0..15 -> cols tc*8..tc*8+7

    // staging: 128 rows x 16 cols = 2048 floats per operand; 256 thr x 2 iters x float4
    const int srow = tid >> 2;          // 0..63
    const int scol = (tid & 3) * 4;     // 0,4,8,12

    float acc[8][8] = {};

    for (int k0 = 0; k0 < D_; k0 += GBK) {
        __syncthreads();
        #pragma unroll
        for (int h = 0; h < 2; ++h) {
            const int r = srow + h * 64;
            float4 zv = *reinterpret_cast<const float4*>(Z + (size_t)(m0 + r) * D_ + k0 + scol);
            Zs[scol + 0][r] = zv.x; Zs[scol + 1][r] = zv.y;
            Zs[scol + 2][r] = zv.z; Zs[scol + 3][r] = zv.w;
            float4 wv = *reinterpret_cast<const float4*>(W + (size_t)(ncol0 + r) * D_ + k0 + scol);
            Ws[scol + 0][r] = wv.x; Ws[scol + 1][r] = wv.y;
            Ws[scol + 2][r] = wv.z; Ws[scol + 3][r] = wv.w;
        }
        __syncthreads();

        #pragma unroll
        for (int kk = 0; kk < GBK; ++kk) {
            float4 a0 = *reinterpret_cast<const float4*>(&Zs[kk][tr * 8]);
            float4 a1 = *reinterpret_cast<const float4*>(&Zs[kk][tr * 8 + 4]);
            float4 b0 = *reinterpret_cast<const float4*>(&Ws[kk][tc * 8]);
            float4 b1 = *reinterpret_cast<const float4*>(&Ws[kk][tc * 8 + 4]);
            const float a[8] = {a0.x, a0.y, a0.z, a0.w, a1.x, a1.y, a1.z, a1.w};
            const float b[8] = {b0.x, b0.y, b0.z, b0.w, b1.x, b1.y, b1.z, b1.w};
            #pragma unroll
            for (int i = 0; i < 8; ++i)
                #pragma unroll
                for (int j = 0; j < 8; ++j)
                    acc[i][j] = fmaf(a[i], b[j], acc[i][j]);
        }
    }

    float* __restrict__ Out = (which == 0) ? Aout : (which == 1) ? Bxout : Cout;
    float bj[8];
    #pragma unroll
    for (int j = 0; j < 8; ++j) bj[j] = bias[ncol0 + tc * 8 + j];

    #pragma unroll
    for (int i = 0; i < 8; ++i) {
        const int m = m0 + tr * 8 + i;
        float* dst = Out + (size_t)m * D_ + ncol0 + tc * 8;
        #pragma unroll
        for (int j = 0; j < 8; ++j) {
            float val = acc[i][j] + bj[j];
            if (which == 0) val = 1.0f / (1.0f + expf(-val));  // sigmoid
            dst[j] = val;
        }
    }
}

// ---------------------------------------------------------------------------
// Chunked scan, replicating reference semantics exactly (P+eps saturation,
// fp32 underflow of the cumprod). Channel = (b, e); chunks of CT timesteps.
// id layout for per-chunk kernels: id = ((b*NC)+c)*D_ + e.
// ---------------------------------------------------------------------------
__global__ __launch_bounds__(256) void scan_chunkprod(
    const float* __restrict__ A, float* __restrict__ LP)
{
    const int id = blockIdx.x * 256 + threadIdx.x;     // 262144
    const int e = id & (D_ - 1);
    const int c = (id >> 10) & (NC - 1);
    const int b = id >> 16;
    size_t base = ((size_t)b * L_ + (size_t)c * CT) * D_ + e;
    float p = 1.0f;
    #pragma unroll 8
    for (int t = 0; t < CT; ++t) p *= A[base + (size_t)t * D_];
    LP[id] = p;
}

__global__ __launch_bounds__(256) void scan_chunkpfx(
    const float* __restrict__ LP, float* __restrict__ Pstart)
{
    const int id = blockIdx.x * 256 + threadIdx.x;  // 4096 channels
    const int e = id & (D_ - 1);
    const int b = id >> 10;
    const size_t base = (size_t)b * NC * D_ + e;
    float p = 1.0f;
    for (int c = 0; c < NC; ++c) {
        Pstart[base + (size_t)c * D_] = p;
        p *= LP[base + (size_t)c * D_];
    }
}

__global__ __launch_bounds__(256) void scan_chunksum(
    const float* __restrict__ A, const float* __restrict__ Bx,
    const float* __restrict__ Pstart, float* __restrict__ Ssum)
{
    const int id = blockIdx.x * 256 + threadIdx.x;
    const int e = id & (D_ - 1);
    const int c = (id >> 10) & (NC - 1);
    const int b = id >> 16;
    size_t base = ((size_t)b * L_ + (size_t)c * CT) * D_ + e;
    float p = Pstart[id];
    float s = 0.0f;
    #pragma unroll 4
    for (int t = 0; t < CT; ++t) {
        const size_t idx = base + (size_t)t * D_;
        p *= A[idx];
        s += Bx[idx] / (p + SCAN_EPS);
    }
    Ssum[id] = s;
}

__global__ __launch_bounds__(256) void scan_sumpfx(
    const float* __restrict__ Ssum, float* __restrict__ Sstart)
{
    const int id = blockIdx.x * 256 + threadIdx.x;  // 4096 channels
    const int e = id & (D_ - 1);
    const int b = id >> 10;
    const size_t base = (size_t)b * NC * D_ + e;
    float s = 0.0f;
    for (int c = 0; c < NC; ++c) {
        Sstart[base + (size_t)c * D_] = s;
        s += Ssum[base + (size_t)c * D_];
    }
}

// Final pass: C lives in d_out (written by GEMM), read & overwritten in place.
__global__ __launch_bounds__(256) void scan_final(
    const float* __restrict__ A, const float* __restrict__ Bx,
    const float* __restrict__ X,
    const float* __restrict__ Pstart, const float* __restrict__ Sstart,
    const float* __restrict__ h0, float* __restrict__ out)
{
    const int id = blockIdx.x * 256 + threadIdx.x;
    const int e = id & (D_ - 1);
    const int c = (id >> 10) & (NC - 1);
    const int b = id >> 16;
    size_t base = ((size_t)b * L_ + (size_t)c * CT) * D_ + e;
    float p = Pstart[id];
    float s = Sstart[id];
    const float h0e = h0[e];
    #pragma unroll 4
    for (int t = 0; t < CT; ++t) {
        const size_t idx = base + (size_t)t * D_;
        p *= A[idx];
        s += Bx[idx] / (p + SCAN_EPS);
        const float h = p * (h0e + s);
        out[idx] = fmaf(out[idx], h, X[idx]);   // out[idx] currently holds C
    }
}

// ---------------------------------------------------------------------------
extern "C" void kernel_launch(void* const* d_in, const int* in_sizes, int n_in,
                              void* d_out, int out_size, void* d_ws, size_t ws_size,
                              hipStream_t stream)
{
    const float* X     = (const float*)d_in[0];
    const float* Wa    = (const float*)d_in[1];
    const float* ba    = (const float*)d_in[2];
    const float* Wb    = (const float*)d_in[3];
    const float* bb    = (const float*)d_in[4];
    const float* Wc    = (const float*)d_in[5];
    const float* bc    = (const float*)d_in[6];
    const float* gamma = (const float*)d_in[7];
    const float* beta  = (const float*)d_in[8];
    const float* h0    = (const float*)d_in[9];
    float* out = (float*)d_out;

    float* ws = (float*)d_ws;
    const size_t NELT = (size_t)M_ * D_;        // 16,777,216
    const size_t NCH  = (size_t)B_ * NC * D_;   // 262,144
    float* Z    = ws;                 // 64 MB
    float* Aarr = Z    + NELT;        // 64 MB
    float* Bxa  = Aarr + NELT;        // 64 MB
    float* LP   = Bxa  + NELT;        // 1 MB
    float* Pst  = LP   + NCH;         // 1 MB
    float* Ssum = Pst  + NCH;         // 1 MB
    float* Sst  = Ssum + NCH;         // 1 MB
    (void)ws_size; (void)in_sizes; (void)n_in; (void)out_size;

    // 1. LayerNorm
    ln_kernel<<<M_, 256, 0, stream>>>(X, gamma, beta, Z);

    // 2. Triple GEMM (A with sigmoid, Bx, C). C is written directly into d_out.
    gemm3_kernel<<<dim3(3072 / GBN, M_ / GBM), 256, 0, stream>>>(
        Z, Wa, ba, Wb, bb, Wc, bc, Aarr, Bxa, out);

    // 3. Chunked scan (exact reference semantics)
    scan_chunkprod<<<1024, 256, 0, stream>>>(Aarr, LP);
    scan_chunkpfx<<<16, 256, 0, stream>>>(LP, Pst);
    scan_chunksum<<<1024, 256, 0, stream>>>(Aarr, Bxa, Pst, Ssum);
    scan_sumpfx<<<16, 256, 0, stream>>>(Ssum, Sst);
    scan_final<<<1024, 256, 0, stream>>>(Aarr, Bxa, X, Pst, Sst, h0, out);
}

// Round 4
// 392.894 us; speedup vs baseline: 3.7637x; 3.7637x over previous
//
#include <hip/hip_runtime.h>
#include <hip/hip_bf16.h>
#include <cstdint>
#include <cstddef>

// Problem constants
#define B_ 4
#define L_ 4096
#define D_ 1024
#define M_ (B_ * L_)          // 16384 rows
#define LN_EPS 1e-5f
#define SCAN_EPS 1e-8f
#define CT 64                 // scan chunk length
#define NC (L_ / CT)          // 64 chunks per sequence

typedef float f32x4 __attribute__((ext_vector_type(4)));
typedef short bf16x8 __attribute__((ext_vector_type(8)));   // 8 bf16 (4 VGPRs)

__device__ __forceinline__ void gload_lds16(const void* g, void* l) {
    __builtin_amdgcn_global_load_lds(
        (const __attribute__((address_space(1))) void*)g,
        (__attribute__((address_space(3))) void*)l, 16, 0, 0);
}

// ---------------------------------------------------------------------------
// LayerNorm over last dim -> bf16 Z. One block (256 thr) per row of 1024.
// ---------------------------------------------------------------------------
__global__ __launch_bounds__(256) void ln_kernel(
    const float* __restrict__ X, const float* __restrict__ gamma,
    const float* __restrict__ beta, __hip_bfloat16* __restrict__ Zb)
{
    const int row = blockIdx.x;
    const int tid = threadIdx.x;
    const float* x = X + (size_t)row * D_;

    float4 v = *reinterpret_cast<const float4*>(x + tid * 4);
    float s = v.x + v.y + v.z + v.w;
    #pragma unroll
    for (int off = 32; off > 0; off >>= 1) s += __shfl_down(s, off);

    __shared__ float red[4];
    __shared__ float red2[4];
    const int wid = tid >> 6, lane = tid & 63;
    if (lane == 0) red[wid] = s;
    __syncthreads();
    const float mean = (red[0] + red[1] + red[2] + red[3]) * (1.0f / D_);

    const float dx = v.x - mean, dy = v.y - mean, dz = v.z - mean, dw = v.w - mean;
    float s2 = dx * dx + dy * dy + dz * dz + dw * dw;
    #pragma unroll
    for (int off = 32; off > 0; off >>= 1) s2 += __shfl_down(s2, off);
    if (lane == 0) red2[wid] = s2;
    __syncthreads();
    const float var = (red2[0] + red2[1] + red2[2] + red2[3]) * (1.0f / D_);
    const float rs = rsqrtf(var + LN_EPS);

    float4 g  = *reinterpret_cast<const float4*>(gamma + tid * 4);
    float4 be = *reinterpret_cast<const float4*>(beta + tid * 4);
    union { ushort4 u4; __hip_bfloat16 h[4]; } pk;
    pk.h[0] = __float2bfloat16(dx * rs * g.x + be.x);
    pk.h[1] = __float2bfloat16(dy * rs * g.y + be.y);
    pk.h[2] = __float2bfloat16(dz * rs * g.z + be.z);
    pk.h[3] = __float2bfloat16(dw * rs * g.w + be.w);
    *reinterpret_cast<ushort4*>(Zb + (size_t)row * D_ + tid * 4) = pk.u4;
}

// ---------------------------------------------------------------------------
// Convert the three D x D fp32 weights to bf16 (contiguous [3][1024][1024]).
// ---------------------------------------------------------------------------
__global__ __launch_bounds__(256) void cvt_w3(
    const float* __restrict__ Wa, const float* __restrict__ Wb,
    const float* __restrict__ Wc, __hip_bfloat16* __restrict__ Wbf)
{
    const int gid = blockIdx.x * 256 + threadIdx.x;       // 393216 threads
    const size_t i = (size_t)gid * 8;
    const int which = (int)(i >> 20);
    const size_t off = i & ((1ull << 20) - 1);
    const float* W = (which == 0) ? Wa : (which == 1) ? Wb : Wc;
    float4 v0 = *reinterpret_cast<const float4*>(W + off);
    float4 v1 = *reinterpret_cast<const float4*>(W + off + 4);
    union { bf16x8 v; __hip_bfloat16 h[8]; } pk;
    pk.h[0] = __float2bfloat16(v0.x); pk.h[1] = __float2bfloat16(v0.y);
    pk.h[2] = __float2bfloat16(v0.z); pk.h[3] = __float2bfloat16(v0.w);
    pk.h[4] = __float2bfloat16(v1.x); pk.h[5] = __float2bfloat16(v1.y);
    pk.h[6] = __float2bfloat16(v1.z); pk.h[7] = __float2bfloat16(v1.w);
    *reinterpret_cast<bf16x8*>(Wbf + i) = pk.v;
}

// ---------------------------------------------------------------------------
// Fused triple GEMM via bf16 MFMA (m97 structure: 128x128 tile, BK=32,
// global_load_lds width16 into XOR-swizzled LDS, 4 waves x 4x4 fragments).
// out[m, e'] = dot(Z[m,:], W[e,:]) + bias ; e' in [0,3072).
// ---------------------------------------------------------------------------
#define TM 128
#define TN 128
#define TK 32

__global__ __launch_bounds__(256) void gemm3_mfma(
    const __hip_bfloat16* __restrict__ Zb, const __hip_bfloat16* __restrict__ Wbf,
    const float* __restrict__ ba, const float* __restrict__ bb, const float* __restrict__ bc,
    float* __restrict__ Aout, float* __restrict__ Bxout, float* __restrict__ Cout)
{
    __shared__ __hip_bfloat16 As[TM * TK];   // 8 KB, chunk-swizzled
    __shared__ __hip_bfloat16 Bs[TN * TK];   // 8 KB

    const int tid  = threadIdx.x;
    const int wv   = tid >> 6;
    const int lane = tid & 63;
    const int wr   = wv >> 1, wc = wv & 1;
    const int m0   = blockIdx.y * TM;
    const int n0g  = blockIdx.x * TN;
    const int which = n0g >> 10;
    const int n0   = n0g & 1023;

    const __hip_bfloat16* __restrict__ Wsrc = Wbf + ((size_t)which << 20);
    const float* __restrict__ bias = (which == 0) ? ba : (which == 1) ? bb : bc;

    // Staging: chunk c (16B) lives at LDS bytes c*16; row=c>>2, ci=c&3.
    // Swizzle: slot(row,ci) holds global chunk ci ^ ((row>>1)&3); read with same XOR.
    const int c0 = tid, c1 = 256 + tid;
    const int row0 = c0 >> 2, sc0 = (c0 & 3) ^ ((row0 >> 1) & 3);
    const int row1 = c1 >> 2, sc1 = (c1 & 3) ^ ((row1 >> 1) & 3);
    // wave-uniform LDS dest bases (HW adds lane*16)
    __hip_bfloat16* aDst0 = As + (size_t)(wv * 64) * 8;
    __hip_bfloat16* aDst1 = As + (size_t)(256 + wv * 64) * 8;
    __hip_bfloat16* bDst0 = Bs + (size_t)(wv * 64) * 8;
    __hip_bfloat16* bDst1 = Bs + (size_t)(256 + wv * 64) * 8;

    f32x4 acc[4][4] = {};

    for (int k0 = 0; k0 < D_; k0 += TK) {
        __syncthreads();   // all waves done reading LDS from previous step
        gload_lds16(Zb   + (size_t)(m0 + row0) * D_ + k0 + sc0 * 8, aDst0);
        gload_lds16(Zb   + (size_t)(m0 + row1) * D_ + k0 + sc1 * 8, aDst1);
        gload_lds16(Wsrc + (size_t)(n0 + row0) * D_ + k0 + sc0 * 8, bDst0);
        gload_lds16(Wsrc + (size_t)(n0 + row1) * D_ + k0 + sc1 * 8, bDst1);
        __syncthreads();   // compiler drains vmcnt before barrier

        bf16x8 af[4], bfr[4];
        const int rl = lane & 15, kg = lane >> 4;
        #pragma unroll
        for (int i = 0; i < 4; ++i) {
            const int ra = wr * 64 + i * 16 + rl;
            af[i] = *reinterpret_cast<const bf16x8*>(
                reinterpret_cast<const char*>(As) + ra * 64 + ((kg ^ ((ra >> 1) & 3)) << 4));
            const int rb = wc * 64 + i * 16 + rl;
            bfr[i] = *reinterpret_cast<const bf16x8*>(
                reinterpret_cast<const char*>(Bs) + rb * 64 + ((kg ^ ((rb >> 1) & 3)) << 4));
        }
        #pragma unroll
        for (int i = 0; i < 4; ++i)
            #pragma unroll
            for (int j = 0; j < 4; ++j)
                acc[i][j] = __builtin_amdgcn_mfma_f32_16x16x32_bf16(
                    af[i], bfr[j], acc[i][j], 0, 0, 0);
    }

    float* __restrict__ Out = (which == 0) ? Aout : (which == 1) ? Bxout : Cout;
    const int cn = n0 + wc * 64 + (lane & 15);
    float bj[4];
    #pragma unroll
    for (int j = 0; j < 4; ++j) bj[j] = bias[cn + j * 16];

    #pragma unroll
    for (int i = 0; i < 4; ++i) {
        #pragma unroll
        for (int r = 0; r < 4; ++r) {
            const int m = m0 + wr * 64 + i * 16 + (lane >> 4) * 4 + r;
            float* dst = Out + (size_t)m * D_ + cn;
            #pragma unroll
            for (int j = 0; j < 4; ++j) {
                float val = acc[i][j][r] + bj[j];
                if (which == 0) val = 1.0f / (1.0f + expf(-val));   // sigmoid gate
                dst[j * 16] = val;
            }
        }
    }
}

// ---------------------------------------------------------------------------
// Chunked scan, replicating reference semantics exactly (P+eps saturation,
// fp32 underflow of the cumprod). Channel = (b, e); chunks of CT timesteps.
// ---------------------------------------------------------------------------
__global__ __launch_bounds__(256) void scan_chunkprod(
    const float* __restrict__ A, float* __restrict__ LP)
{
    const int id = blockIdx.x * 256 + threadIdx.x;     // 262144
    const int e = id & (D_ - 1);
    const int c = (id >> 10) & (NC - 1);
    const int b = id >> 16;
    size_t base = ((size_t)b * L_ + (size_t)c * CT) * D_ + e;
    float p = 1.0f;
    #pragma unroll 8
    for (int t = 0; t < CT; ++t) p *= A[base + (size_t)t * D_];
    LP[id] = p;
}

__global__ __launch_bounds__(256) void scan_chunkpfx(
    const float* __restrict__ LP, float* __restrict__ Pstart)
{
    const int id = blockIdx.x * 256 + threadIdx.x;  // 4096 channels
    const int e = id & (D_ - 1);
    const int b = id >> 10;
    const size_t base = (size_t)b * NC * D_ + e;
    float p = 1.0f;
    for (int c = 0; c < NC; ++c) {
        Pstart[base + (size_t)c * D_] = p;
        p *= LP[base + (size_t)c * D_];
    }
}

__global__ __launch_bounds__(256) void scan_chunksum(
    const float* __restrict__ A, const float* __restrict__ Bx,
    const float* __restrict__ Pstart, float* __restrict__ Ssum)
{
    const int id = blockIdx.x * 256 + threadIdx.x;
    const int e = id & (D_ - 1);
    const int c = (id >> 10) & (NC - 1);
    const int b = id >> 16;
    size_t base = ((size_t)b * L_ + (size_t)c * CT) * D_ + e;
    float p = Pstart[id];
    float s = 0.0f;
    #pragma unroll 4
    for (int t = 0; t < CT; ++t) {
        const size_t idx = base + (size_t)t * D_;
        p *= A[idx];
        s += Bx[idx] / (p + SCAN_EPS);
    }
    Ssum[id] = s;
}

__global__ __launch_bounds__(256) void scan_sumpfx(
    const float* __restrict__ Ssum, float* __restrict__ Sstart)
{
    const int id = blockIdx.x * 256 + threadIdx.x;  // 4096 channels
    const int e = id & (D_ - 1);
    const int b = id >> 10;
    const size_t base = (size_t)b * NC * D_ + e;
    float s = 0.0f;
    for (int c = 0; c < NC; ++c) {
        Sstart[base + (size_t)c * D_] = s;
        s += Ssum[base + (size_t)c * D_];
    }
}

// Final pass: C lives in d_out (written by GEMM), read & overwritten in place.
__global__ __launch_bounds__(256) void scan_final(
    const float* __restrict__ A, const float* __restrict__ Bx,
    const float* __restrict__ X,
    const float* __restrict__ Pstart, const float* __restrict__ Sstart,
    const float* __restrict__ h0, float* __restrict__ out)
{
    const int id = blockIdx.x * 256 + threadIdx.x;
    const int e = id & (D_ - 1);
    const int c = (id >> 10) & (NC - 1);
    const int b = id >> 16;
    size_t base = ((size_t)b * L_ + (size_t)c * CT) * D_ + e;
    float p = Pstart[id];
    float s = Sstart[id];
    const float h0e = h0[e];
    #pragma unroll 4
    for (int t = 0; t < CT; ++t) {
        const size_t idx = base + (size_t)t * D_;
        p *= A[idx];
        s += Bx[idx] / (p + SCAN_EPS);
        const float h = p * (h0e + s);
        out[idx] = fmaf(out[idx], h, X[idx]);   // out[idx] currently holds C
    }
}

// ---------------------------------------------------------------------------
extern "C" void kernel_launch(void* const* d_in, const int* in_sizes, int n_in,
                              void* d_out, int out_size, void* d_ws, size_t ws_size,
                              hipStream_t stream)
{
    const float* X     = (const float*)d_in[0];
    const float* Wa    = (const float*)d_in[1];
    const float* ba    = (const float*)d_in[2];
    const float* Wb    = (const float*)d_in[3];
    const float* bb    = (const float*)d_in[4];
    const float* Wc    = (const float*)d_in[5];
    const float* bc    = (const float*)d_in[6];
    const float* gamma = (const float*)d_in[7];
    const float* beta  = (const float*)d_in[8];
    const float* h0    = (const float*)d_in[9];
    float* out = (float*)d_out;

    const size_t NELT = (size_t)M_ * D_;        // 16,777,216
    const size_t NCH  = (size_t)B_ * NC * D_;   // 262,144

    __hip_bfloat16* Zb  = (__hip_bfloat16*)d_ws;            // 32 MB
    __hip_bfloat16* Wbf = Zb + NELT;                         // 6 MB
    float* Aarr = (float*)(Wbf + 3ull * 1024 * 1024);        // 64 MB
    float* Bxa  = Aarr + NELT;                               // 64 MB
    float* LP   = Bxa  + NELT;                               // 1 MB
    float* Pst  = LP   + NCH;
    float* Ssum = Pst  + NCH;
    float* Sst  = Ssum + NCH;
    (void)ws_size; (void)in_sizes; (void)n_in; (void)out_size;

    // 1. Weight bf16 conversion + LayerNorm (independent)
    cvt_w3<<<1536, 256, 0, stream>>>(Wa, Wb, Wc, Wbf);
    ln_kernel<<<M_, 256, 0, stream>>>(X, gamma, beta, Zb);

    // 2. Fused triple GEMM via MFMA (A + sigmoid, Bx, C->d_out)
    gemm3_mfma<<<dim3(3072 / TN, M_ / TM), 256, 0, stream>>>(
        Zb, Wbf, ba, bb, bc, Aarr, Bxa, out);

    // 3. Chunked scan (exact reference semantics)
    scan_chunkprod<<<1024, 256, 0, stream>>>(Aarr, LP);
    scan_chunkpfx<<<16, 256, 0, stream>>>(LP, Pst);
    scan_chunksum<<<1024, 256, 0, stream>>>(Aarr, Bxa, Pst, Ssum);
    scan_sumpfx<<<16, 256, 0, stream>>>(Ssum, Sst);
    scan_final<<<1024, 256, 0, stream>>>(Aarr, Bxa, X, Pst, Sst, h0, out);
}

// Round 6
// 352.163 us; speedup vs baseline: 4.1991x; 1.1157x over previous
//
#include <hip/hip_runtime.h>
#include <hip/hip_bf16.h>
#include <cstdint>
#include <cstddef>

// Problem constants
#define B_ 4
#define L_ 4096
#define D_ 1024
#define M_ (B_ * L_)          // 16384 rows
#define LN_EPS 1e-5f
#define SCAN_EPS 1e-8f
#define CT 64                 // scan chunk length == GEMM wave row-span
#define NC (L_ / CT)          // 64 chunks per sequence

typedef float f32x4 __attribute__((ext_vector_type(4)));
typedef short bf16x8 __attribute__((ext_vector_type(8)));   // 8 bf16 (4 VGPRs)

__device__ __forceinline__ void gload_lds16(const void* g, void* l) {
    __builtin_amdgcn_global_load_lds(
        (const __attribute__((address_space(1))) void*)g,
        (__attribute__((address_space(3))) void*)l, 16, 0, 0);
}

// ---------------------------------------------------------------------------
// LayerNorm over last dim -> bf16 Z. One block (256 thr) per row of 1024.
// ---------------------------------------------------------------------------
__global__ __launch_bounds__(256) void ln_kernel(
    const float* __restrict__ X, const float* __restrict__ gamma,
    const float* __restrict__ beta, __hip_bfloat16* __restrict__ Zb)
{
    const int row = blockIdx.x;
    const int tid = threadIdx.x;
    const float* x = X + (size_t)row * D_;

    float4 v = *reinterpret_cast<const float4*>(x + tid * 4);
    float s = v.x + v.y + v.z + v.w;
    #pragma unroll
    for (int off = 32; off > 0; off >>= 1) s += __shfl_down(s, off);

    __shared__ float red[4];
    __shared__ float red2[4];
    const int wid = tid >> 6, lane = tid & 63;
    if (lane == 0) red[wid] = s;
    __syncthreads();
    const float mean = (red[0] + red[1] + red[2] + red[3]) * (1.0f / D_);

    const float dx = v.x - mean, dy = v.y - mean, dz = v.z - mean, dw = v.w - mean;
    float s2 = dx * dx + dy * dy + dz * dz + dw * dw;
    #pragma unroll
    for (int off = 32; off > 0; off >>= 1) s2 += __shfl_down(s2, off);
    if (lane == 0) red2[wid] = s2;
    __syncthreads();
    const float var = (red2[0] + red2[1] + red2[2] + red2[3]) * (1.0f / D_);
    const float rs = rsqrtf(var + LN_EPS);

    float4 g  = *reinterpret_cast<const float4*>(gamma + tid * 4);
    float4 be = *reinterpret_cast<const float4*>(beta + tid * 4);
    union { ushort4 u4; __hip_bfloat16 h[4]; } pk;
    pk.h[0] = __float2bfloat16(dx * rs * g.x + be.x);
    pk.h[1] = __float2bfloat16(dy * rs * g.y + be.y);
    pk.h[2] = __float2bfloat16(dz * rs * g.z + be.z);
    pk.h[3] = __float2bfloat16(dw * rs * g.w + be.w);
    *reinterpret_cast<ushort4*>(Zb + (size_t)row * D_ + tid * 4) = pk.u4;
}

// ---------------------------------------------------------------------------
// Convert the three D x D fp32 weights to bf16 (contiguous [3][1024][1024]).
// ---------------------------------------------------------------------------
__global__ __launch_bounds__(256) void cvt_w3(
    const float* __restrict__ Wa, const float* __restrict__ Wb,
    const float* __restrict__ Wc, __hip_bfloat16* __restrict__ Wbf)
{
    const int gid = blockIdx.x * 256 + threadIdx.x;       // 393216 threads
    const size_t i = (size_t)gid * 8;
    const int which = (int)(i >> 20);
    const size_t off = i & ((1ull << 20) - 1);
    const float* W = (which == 0) ? Wa : (which == 1) ? Wb : Wc;
    float4 v0 = *reinterpret_cast<const float4*>(W + off);
    float4 v1 = *reinterpret_cast<const float4*>(W + off + 4);
    union { bf16x8 v; __hip_bfloat16 h[8]; } pk;
    pk.h[0] = __float2bfloat16(v0.x); pk.h[1] = __float2bfloat16(v0.y);
    pk.h[2] = __float2bfloat16(v0.z); pk.h[3] = __float2bfloat16(v0.w);
    pk.h[4] = __float2bfloat16(v1.x); pk.h[5] = __float2bfloat16(v1.y);
    pk.h[6] = __float2bfloat16(v1.z); pk.h[7] = __float2bfloat16(v1.w);
    *reinterpret_cast<bf16x8*>(Wbf + i) = pk.v;
}

// ---------------------------------------------------------------------------
// Fused triple GEMM via bf16 MFMA (m97 structure: 128x128 tile, BK=32,
// global_load_lds width16 into XOR-swizzled LDS, 4 waves x 4x4 fragments).
// Outputs stored bf16. which==0 (gate A) additionally computes each 64-row
// chunk's cumulative product from the accumulator (one wave == one chunk's
// rows) and writes LP — this replaces the scan_chunkprod pass entirely.
// ---------------------------------------------------------------------------
#define TM 128
#define TN 128
#define TK 32

__global__ __launch_bounds__(256) void gemm3_mfma(
    const __hip_bfloat16* __restrict__ Zb, const __hip_bfloat16* __restrict__ Wbf,
    const float* __restrict__ ba, const float* __restrict__ bb, const float* __restrict__ bc,
    __hip_bfloat16* __restrict__ Aout, __hip_bfloat16* __restrict__ Bxout,
    __hip_bfloat16* __restrict__ Cout, float* __restrict__ LP)
{
    __shared__ __hip_bfloat16 As[TM * TK];   // 8 KB, chunk-swizzled
    __shared__ __hip_bfloat16 Bs[TN * TK];   // 8 KB

    const int tid  = threadIdx.x;
    const int wv   = tid >> 6;
    const int lane = tid & 63;
    const int wr   = wv >> 1, wc = wv & 1;
    const int m0   = blockIdx.y * TM;
    const int n0g  = blockIdx.x * TN;
    const int which = n0g >> 10;
    const int n0   = n0g & 1023;

    const __hip_bfloat16* __restrict__ Wsrc = Wbf + ((size_t)which << 20);
    const float* __restrict__ bias = (which == 0) ? ba : (which == 1) ? bb : bc;

    // Staging: chunk c (16B) lives at LDS bytes c*16; row=c>>2, ci=c&3.
    // Swizzle: slot(row,ci) holds global chunk ci ^ ((row>>1)&3); read with same XOR.
    const int c0 = tid, c1 = 256 + tid;
    const int row0 = c0 >> 2, sc0 = (c0 & 3) ^ ((row0 >> 1) & 3);
    const int row1 = c1 >> 2, sc1 = (c1 & 3) ^ ((row1 >> 1) & 3);
    // wave-uniform LDS dest bases (HW adds lane*16)
    __hip_bfloat16* aDst0 = As + (size_t)(wv * 64) * 8;
    __hip_bfloat16* aDst1 = As + (size_t)(256 + wv * 64) * 8;
    __hip_bfloat16* bDst0 = Bs + (size_t)(wv * 64) * 8;
    __hip_bfloat16* bDst1 = Bs + (size_t)(256 + wv * 64) * 8;

    f32x4 acc[4][4] = {};

    for (int k0 = 0; k0 < D_; k0 += TK) {
        __syncthreads();   // all waves done reading LDS from previous step
        gload_lds16(Zb   + (size_t)(m0 + row0) * D_ + k0 + sc0 * 8, aDst0);
        gload_lds16(Zb   + (size_t)(m0 + row1) * D_ + k0 + sc1 * 8, aDst1);
        gload_lds16(Wsrc + (size_t)(n0 + row0) * D_ + k0 + sc0 * 8, bDst0);
        gload_lds16(Wsrc + (size_t)(n0 + row1) * D_ + k0 + sc1 * 8, bDst1);
        __syncthreads();   // compiler drains vmcnt before barrier

        bf16x8 af[4], bfr[4];
        const int rl = lane & 15, kg = lane >> 4;
        #pragma unroll
        for (int i = 0; i < 4; ++i) {
            const int ra = wr * 64 + i * 16 + rl;
            af[i] = *reinterpret_cast<const bf16x8*>(
                reinterpret_cast<const char*>(As) + ra * 64 + ((kg ^ ((ra >> 1) & 3)) << 4));
            const int rb = wc * 64 + i * 16 + rl;
            bfr[i] = *reinterpret_cast<const bf16x8*>(
                reinterpret_cast<const char*>(Bs) + rb * 64 + ((kg ^ ((rb >> 1) & 3)) << 4));
        }
        #pragma unroll
        for (int i = 0; i < 4; ++i)
            #pragma unroll
            for (int j = 0; j < 4; ++j)
                acc[i][j] = __builtin_amdgcn_mfma_f32_16x16x32_bf16(
                    af[i], bfr[j], acc[i][j], 0, 0, 0);
    }

    const int cn = n0 + wc * 64 + (lane & 15);
    float bj[4];
    #pragma unroll
    for (int j = 0; j < 4; ++j) bj[j] = bias[cn + j * 16];

    if (which == 0) {
        // Gate A: sigmoid -> bf16 store; accumulate this wave's 64-row chunk
        // product per column from the SAME bf16-rounded values the scan reads.
        float pp[4] = {1.0f, 1.0f, 1.0f, 1.0f};
        #pragma unroll
        for (int i = 0; i < 4; ++i) {
            #pragma unroll
            for (int r = 0; r < 4; ++r) {
                const int m = m0 + wr * 64 + i * 16 + (lane >> 4) * 4 + r;
                __hip_bfloat16* dst = Aout + (size_t)m * D_ + cn;
                #pragma unroll
                for (int j = 0; j < 4; ++j) {
                    const float val = 1.0f / (1.0f + expf(-(acc[i][j][r] + bj[j])));
                    const __hip_bfloat16 hb = __float2bfloat16(val);
                    dst[j * 16] = hb;
                    pp[j] *= __bfloat162float(hb);
                }
            }
        }
        // product across the 4 kg row-groups (lane^16, lane^32 butterflies)
        #pragma unroll
        for (int j = 0; j < 4; ++j) {
            pp[j] *= __shfl_xor(pp[j], 16);
            pp[j] *= __shfl_xor(pp[j], 32);
        }
        const int rl = lane & 15, kg = lane >> 4;
        const float sel = (kg == 0) ? pp[0] : (kg == 1) ? pp[1] : (kg == 2) ? pp[2] : pp[3];
        const int bseq = m0 >> 12;                 // sequence index
        const int cidx = ((m0 & 4095) >> 6) + wr;  // chunk index within sequence
        LP[((size_t)bseq * NC + cidx) * D_ + n0 + wc * 64 + kg * 16 + rl] = sel;
    } else {
        __hip_bfloat16* __restrict__ Out = (which == 1) ? Bxout : Cout;
        #pragma unroll
        for (int i = 0; i < 4; ++i) {
            #pragma unroll
            for (int r = 0; r < 4; ++r) {
                const int m = m0 + wr * 64 + i * 16 + (lane >> 4) * 4 + r;
                __hip_bfloat16* dst = Out + (size_t)m * D_ + cn;
                #pragma unroll
                for (int j = 0; j < 4; ++j)
                    dst[j * 16] = __float2bfloat16(acc[i][j][r] + bj[j]);
            }
        }
    }
}

// ---------------------------------------------------------------------------
// Chunked scan on bf16 A/Bx/C (fp32 arithmetic, exact eps/underflow semantics).
// ---------------------------------------------------------------------------
__global__ __launch_bounds__(256) void scan_chunkpfx(
    const float* __restrict__ LP, float* __restrict__ Pstart)
{
    const int id = blockIdx.x * 256 + threadIdx.x;  // 4096 channels
    const int e = id & (D_ - 1);
    const int b = id >> 10;
    const size_t base = (size_t)b * NC * D_ + e;
    float p = 1.0f;
    for (int c = 0; c < NC; ++c) {
        Pstart[base + (size_t)c * D_] = p;
        p *= LP[base + (size_t)c * D_];
    }
}

__global__ __launch_bounds__(256) void scan_chunksum(
    const __hip_bfloat16* __restrict__ A, const __hip_bfloat16* __restrict__ Bx,
    const float* __restrict__ Pstart, float* __restrict__ Ssum)
{
    const int id = blockIdx.x * 256 + threadIdx.x;
    const int e = id & (D_ - 1);
    const int c = (id >> 10) & (NC - 1);
    const int b = id >> 16;
    size_t base = ((size_t)b * L_ + (size_t)c * CT) * D_ + e;
    float p = Pstart[id];
    float s = 0.0f;
    #pragma unroll 4
    for (int t = 0; t < CT; ++t) {
        const size_t idx = base + (size_t)t * D_;
        p *= __bfloat162float(A[idx]);
        s += __bfloat162float(Bx[idx]) / (p + SCAN_EPS);
    }
    Ssum[id] = s;
}

__global__ __launch_bounds__(256) void scan_sumpfx(
    const float* __restrict__ Ssum, float* __restrict__ Sstart)
{
    const int id = blockIdx.x * 256 + threadIdx.x;  // 4096 channels
    const int e = id & (D_ - 1);
    const int b = id >> 10;
    const size_t base = (size_t)b * NC * D_ + e;
    float s = 0.0f;
    for (int c = 0; c < NC; ++c) {
        Sstart[base + (size_t)c * D_] = s;
        s += Ssum[base + (size_t)c * D_];
    }
}

__global__ __launch_bounds__(256) void scan_final(
    const __hip_bfloat16* __restrict__ A, const __hip_bfloat16* __restrict__ Bx,
    const __hip_bfloat16* __restrict__ C, const float* __restrict__ X,
    const float* __restrict__ Pstart, const float* __restrict__ Sstart,
    const float* __restrict__ h0, float* __restrict__ out)
{
    const int id = blockIdx.x * 256 + threadIdx.x;
    const int e = id & (D_ - 1);
    const int c = (id >> 10) & (NC - 1);
    const int b = id >> 16;
    size_t base = ((size_t)b * L_ + (size_t)c * CT) * D_ + e;
    float p = Pstart[id];
    float s = Sstart[id];
    const float h0e = h0[e];
    #pragma unroll 4
    for (int t = 0; t < CT; ++t) {
        const size_t idx = base + (size_t)t * D_;
        p *= __bfloat162float(A[idx]);
        s += __bfloat162float(Bx[idx]) / (p + SCAN_EPS);
        const float h = p * (h0e + s);
        out[idx] = fmaf(__bfloat162float(C[idx]), h, X[idx]);
    }
}

// ---------------------------------------------------------------------------
extern "C" void kernel_launch(void* const* d_in, const int* in_sizes, int n_in,
                              void* d_out, int out_size, void* d_ws, size_t ws_size,
                              hipStream_t stream)
{
    const float* X     = (const float*)d_in[0];
    const float* Wa    = (const float*)d_in[1];
    const float* ba    = (const float*)d_in[2];
    const float* Wb    = (const float*)d_in[3];
    const float* bb    = (const float*)d_in[4];
    const float* Wc    = (const float*)d_in[5];
    const float* bc    = (const float*)d_in[6];
    const float* gamma = (const float*)d_in[7];
    const float* beta  = (const float*)d_in[8];
    const float* h0    = (const float*)d_in[9];
    float* out = (float*)d_out;

    const size_t NELT = (size_t)M_ * D_;        // 16,777,216
    const size_t NCH  = (size_t)B_ * NC * D_;   // 262,144

    __hip_bfloat16* Zb   = (__hip_bfloat16*)d_ws;           // 32 MB
    __hip_bfloat16* Wbf  = Zb + NELT;                        // 6 MB
    __hip_bfloat16* Abf  = Wbf + 3ull * 1024 * 1024;         // 32 MB
    __hip_bfloat16* Bxbf = Abf + NELT;                       // 32 MB
    __hip_bfloat16* Cbf  = Bxbf + NELT;                      // 32 MB
    float* LP   = (float*)(Cbf + NELT);                      // 1 MB
    float* Pst  = LP   + NCH;
    float* Ssum = Pst  + NCH;
    float* Sst  = Ssum + NCH;
    (void)ws_size; (void)in_sizes; (void)n_in; (void)out_size;

    // 1. Weight bf16 conversion + LayerNorm (independent)
    cvt_w3<<<1536, 256, 0, stream>>>(Wa, Wb, Wc, Wbf);
    ln_kernel<<<M_, 256, 0, stream>>>(X, gamma, beta, Zb);

    // 2. Fused triple GEMM via MFMA; also emits per-chunk gate products (LP).
    gemm3_mfma<<<dim3(3072 / TN, M_ / TM), 256, 0, stream>>>(
        Zb, Wbf, ba, bb, bc, Abf, Bxbf, Cbf, LP);

    // 3. Chunked scan (exact reference semantics; chunkprod now fused in GEMM)
    scan_chunkpfx<<<16, 256, 0, stream>>>(LP, Pst);
    scan_chunksum<<<1024, 256, 0, stream>>>(Abf, Bxbf, Pst, Ssum);
    scan_sumpfx<<<16, 256, 0, stream>>>(Ssum, Sst);
    scan_final<<<1024, 256, 0, stream>>>(Abf, Bxbf, Cbf, X, Pst, Sst, h0, out);
}